// Round 1
// baseline (1006.675 us; speedup 1.0000x reference)
//
#include <hip/hip_runtime.h>

#define HID 64
#define IN_CH 128

// ---------------- degree kernels ----------------
__global__ __launch_bounds__(256) void deg_init_kernel(float* deg, int n) {
    int i = blockIdx.x * 256 + threadIdx.x;
    if (i < n) deg[i] = 1.0f;  // self-loop
}

__global__ __launch_bounds__(256) void deg_count_kernel(const int* __restrict__ dst,
                                                        float* deg, int E) {
    int e = blockIdx.x * 256 + threadIdx.x;
    if (e < E) atomicAdd(&deg[dst[e]], 1.0f);
}

__global__ __launch_bounds__(256) void deg_rsqrt_kernel(float* deg, int n) {
    int i = blockIdx.x * 256 + threadIdx.x;
    if (i < n) deg[i] = rsqrtf(deg[i]);  // deg >= 1 always
}

// ---------------- GEMM: out = A[N,K] @ W[K,64] ----------------
// ROWS rows per block, 256 threads, each thread computes (ROWS/16) x 4 outputs.
// FUSE=false: Bout = A@W + bias   (input projection)
// FUSE=true : Bout = A@W ; Cout = bias + (A@W) * dinv[row]^2   (agg self-loop init)
template <int K, int ROWS, bool FUSE>
__global__ __launch_bounds__(256) void gemm_kernel(
    const float* __restrict__ A, const float* __restrict__ W,
    const float* __restrict__ bias, const float* __restrict__ dinv,
    float* __restrict__ Bout, float* __restrict__ Cout, int N) {
    constexpr int PAD = 4;
    constexpr int RT = ROWS / 16;  // rows per thread
    __shared__ float ws[K * HID];
    __shared__ float as[ROWS * (K + PAD)];

    const int tid = threadIdx.x;
    const int row_base = blockIdx.x * ROWS;

    for (int i = tid; i < K * HID; i += 256) ws[i] = W[i];
    for (int i = tid; i < ROWS * K; i += 256) {
        int r = i / K, k = i - r * K;
        int gr = row_base + r;
        as[r * (K + PAD) + k] = (gr < N) ? A[(size_t)gr * K + k] : 0.0f;
    }
    __syncthreads();

    const int tx = tid & 15, ty = tid >> 4;
    const int c0 = tx * 4, r0 = ty * RT;

    float acc[RT][4];
#pragma unroll
    for (int j = 0; j < RT; j++)
#pragma unroll
        for (int i2 = 0; i2 < 4; i2++) acc[j][i2] = 0.0f;

    for (int k = 0; k < K; k += 4) {
        float4 av[RT], wv[4];
#pragma unroll
        for (int j = 0; j < RT; j++)
            av[j] = *(const float4*)&as[(r0 + j) * (K + PAD) + k];
#pragma unroll
        for (int kk = 0; kk < 4; kk++)
            wv[kk] = *(const float4*)&ws[(k + kk) * HID + c0];
#pragma unroll
        for (int j = 0; j < RT; j++) {
#pragma unroll
            for (int kk = 0; kk < 4; kk++) {
                const float a = (&av[j].x)[kk];
                acc[j][0] += a * wv[kk].x;
                acc[j][1] += a * wv[kk].y;
                acc[j][2] += a * wv[kk].z;
                acc[j][3] += a * wv[kk].w;
            }
        }
    }

    const float4 bv = *(const float4*)&bias[c0];
#pragma unroll
    for (int j = 0; j < RT; j++) {
        const int gr = row_base + r0 + j;
        if (gr < N) {
            float4 v = make_float4(acc[j][0], acc[j][1], acc[j][2], acc[j][3]);
            const size_t o = (size_t)gr * HID + c0;
            if (FUSE) {
                *(float4*)&Bout[o] = v;
                const float di = dinv[gr];
                const float d2 = di * di;
                float4 cv = make_float4(bv.x + v.x * d2, bv.y + v.y * d2,
                                        bv.z + v.z * d2, bv.w + v.w * d2);
                *(float4*)&Cout[o] = cv;
            } else {
                float4 ov = make_float4(v.x + bv.x, v.y + bv.y, v.z + bv.z, v.w + bv.w);
                *(float4*)&Bout[o] = ov;
            }
        }
    }
}

// ---------------- edge scatter-add: one wave per edge, lane = channel ------
__global__ __launch_bounds__(256) void edge_agg_kernel(
    const int* __restrict__ src, const int* __restrict__ dst,
    const float* __restrict__ dinv, const float* __restrict__ hw,
    float* __restrict__ agg, int E) {
    const long long tid = (long long)blockIdx.x * 256 + threadIdx.x;
    const int e = (int)(tid >> 6);
    const int c = threadIdx.x & 63;
    if (e < E) {
        const int s = src[e];
        const int d = dst[e];
        const float norm = dinv[s] * dinv[d];
        atomicAdd(&agg[(size_t)d * HID + c], hw[(size_t)s * HID + c] * norm);
    }
}

// ---------------- LayerNorm (+ relu + residual update) ----------------
// one wave per row; LAST=false: res = relu(LN(C)) + res ; LAST=true: out = LN(C)
template <bool LAST>
__global__ __launch_bounds__(256) void ln_kernel(
    const float* __restrict__ C, const float* __restrict__ g,
    const float* __restrict__ beta, float* __restrict__ res,
    float* __restrict__ out, int N) {
    const int row = blockIdx.x * 4 + (threadIdx.x >> 6);
    const int c = threadIdx.x & 63;
    if (row >= N) return;
    const size_t o = (size_t)row * HID + c;
    const float v = C[o];
    float s = v;
#pragma unroll
    for (int m = 1; m < 64; m <<= 1) s += __shfl_xor(s, m);
    const float mean = s * (1.0f / 64.0f);
    const float d = v - mean;
    float q = d * d;
#pragma unroll
    for (int m = 1; m < 64; m <<= 1) q += __shfl_xor(q, m);
    const float var = q * (1.0f / 64.0f);
    const float y = d * rsqrtf(var + 1e-5f) * g[c] + beta[c];
    if (LAST) {
        out[o] = y;
    } else {
        const float r = fmaxf(y, 0.0f) + res[o];
        res[o] = r;
    }
}

extern "C" void kernel_launch(void* const* d_in, const int* in_sizes, int n_in,
                              void* d_out, int out_size, void* d_ws, size_t ws_size,
                              hipStream_t stream) {
    const float* x      = (const float*)d_in[0];
    const int*   ei     = (const int*)d_in[1];
    const float* proj_w = (const float*)d_in[2];
    const float* proj_b = (const float*)d_in[3];
    const float* w[3]  = {(const float*)d_in[4], (const float*)d_in[8],  (const float*)d_in[12]};
    const float* b[3]  = {(const float*)d_in[5], (const float*)d_in[9],  (const float*)d_in[13]};
    const float* g[3]  = {(const float*)d_in[6], (const float*)d_in[10], (const float*)d_in[14]};
    const float* be[3] = {(const float*)d_in[7], (const float*)d_in[11], (const float*)d_in[15]};

    const int N = in_sizes[0] / IN_CH;
    const int E = in_sizes[1] / 2;
    const int* src = ei;
    const int* dst = ei + E;

    char* wsb = (char*)d_ws;
    float* deg = (float*)wsb;
    size_t off = ((size_t)N * 4 + 255) & ~(size_t)255;
    float* Abuf = (float*)(wsb + off); off += (size_t)N * HID * 4;   // h / residual
    float* Bbuf = (float*)(wsb + off); off += (size_t)N * HID * 4;   // hw
    float* Cbuf = (float*)(wsb + off);                               // agg

    // degrees -> dinv
    deg_init_kernel<<<(N + 255) / 256, 256, 0, stream>>>(deg, N);
    deg_count_kernel<<<(E + 255) / 256, 256, 0, stream>>>(dst, deg, E);
    deg_rsqrt_kernel<<<(N + 255) / 256, 256, 0, stream>>>(deg, N);

    // input projection: A = x @ proj_w + proj_b
    gemm_kernel<IN_CH, 32, false><<<(N + 31) / 32, 256, 0, stream>>>(
        x, proj_w, proj_b, nullptr, Abuf, nullptr, N);

    const long long edge_threads = (long long)E * 64;
    const int edge_blocks = (int)((edge_threads + 255) / 256);

    for (int l = 0; l < 3; l++) {
        // B = A @ w[l]; C = b[l] + B * dinv^2  (self-loop init)
        gemm_kernel<HID, 64, true><<<(N + 63) / 64, 256, 0, stream>>>(
            Abuf, w[l], b[l], deg, Bbuf, Cbuf, N);
        // C[dst] += B[src] * dinv[src]*dinv[dst]
        edge_agg_kernel<<<edge_blocks, 256, 0, stream>>>(src, dst, deg, Bbuf, Cbuf, E);
        if (l < 2) {
            ln_kernel<false><<<(N + 3) / 4, 256, 0, stream>>>(
                Cbuf, g[l], be[l], Abuf, nullptr, N);
        } else {
            ln_kernel<true><<<(N + 3) / 4, 256, 0, stream>>>(
                Cbuf, g[l], be[l], nullptr, (float*)d_out, N);
        }
    }
}

// Round 2
// 568.377 us; speedup vs baseline: 1.7711x; 1.7711x over previous
//
#include <hip/hip_runtime.h>

#define HID 64
#define IN_CH 128

// ============ CSR build: histogram -> scan -> scatter ============

__global__ __launch_bounds__(256) void hist_kernel(const int* __restrict__ dst,
                                                   int* __restrict__ cnt, int E) {
    int e = blockIdx.x * 256 + threadIdx.x;
    if (e < E) atomicAdd(&cnt[dst[e]], 1);
}

__global__ __launch_bounds__(256) void block_sum_kernel(const int* __restrict__ cnt,
                                                        int* __restrict__ bsum, int N) {
    int i = blockIdx.x * 256 + threadIdx.x;
    int v = (i < N) ? cnt[i] : 0;
#pragma unroll
    for (int m = 1; m < 64; m <<= 1) v += __shfl_xor(v, m);
    __shared__ int wsm[4];
    if ((threadIdx.x & 63) == 0) wsm[threadIdx.x >> 6] = v;
    __syncthreads();
    if (threadIdx.x == 0) bsum[blockIdx.x] = wsm[0] + wsm[1] + wsm[2] + wsm[3];
}

// single block, 512 threads, chunked Hillis-Steele exclusive scan of bsum
__global__ __launch_bounds__(512) void scan_bsum_kernel(int* __restrict__ bsum,
                                                        int* __restrict__ off,
                                                        int NB, int N, int E) {
    __shared__ int sm[512];
    __shared__ int carry;
    const int t = threadIdx.x;
    if (t == 0) carry = 0;
    __syncthreads();
    for (int base = 0; base < NB; base += 512) {
        const int idx = base + t;
        const int v = (idx < NB) ? bsum[idx] : 0;
        sm[t] = v;
        __syncthreads();
        for (int d = 1; d < 512; d <<= 1) {
            int x = sm[t];
            int y = (t >= d) ? sm[t - d] : 0;
            __syncthreads();
            sm[t] = x + y;
            __syncthreads();
        }
        if (idx < NB) bsum[idx] = carry + sm[t] - v;
        __syncthreads();
        if (t == 0) carry += sm[511];
        __syncthreads();
    }
    if (t == 0) off[N] = E;
}

__global__ __launch_bounds__(256) void block_scan_kernel(const int* __restrict__ cnt,
                                                         const int* __restrict__ bsum,
                                                         int* __restrict__ off, int N) {
    __shared__ int sm[256];
    const int i = blockIdx.x * 256 + threadIdx.x;
    const int t = threadIdx.x;
    const int v = (i < N) ? cnt[i] : 0;
    sm[t] = v;
    __syncthreads();
    for (int d = 1; d < 256; d <<= 1) {
        int x = sm[t];
        int y = (t >= d) ? sm[t - d] : 0;
        __syncthreads();
        sm[t] = x + y;
        __syncthreads();
    }
    if (i < N) off[i] = bsum[blockIdx.x] + sm[t] - v;  // exclusive
}

__global__ __launch_bounds__(256) void dinv_kernel(const int* __restrict__ cnt,
                                                   float* __restrict__ dinv, int N) {
    int i = blockIdx.x * 256 + threadIdx.x;
    if (i < N) dinv[i] = rsqrtf((float)cnt[i] + 1.0f);  // +1 self-loop
}

__global__ __launch_bounds__(256) void scatter_kernel(
    const int* __restrict__ src, const int* __restrict__ dst,
    const int* __restrict__ off, int* __restrict__ pos,
    const float* __restrict__ dinv, int* __restrict__ ssrc,
    float* __restrict__ snorm, int E) {
    int e = blockIdx.x * 256 + threadIdx.x;
    if (e < E) {
        const int d = dst[e];
        const int s = src[e];
        const int p = off[d] + atomicAdd(&pos[d], 1);
        ssrc[p] = s;
        snorm[p] = dinv[s] * dinv[d];
    }
}

// ============ GEMM: Bout = A[N,K] @ W[K,64] (+bias) ============
template <int K, int ROWS, bool ADD_BIAS>
__global__ __launch_bounds__(256) void gemm_kernel(
    const float* __restrict__ A, const float* __restrict__ W,
    const float* __restrict__ bias, float* __restrict__ Bout, int N) {
    constexpr int PAD = 4;
    constexpr int RT = ROWS / 16;
    __shared__ float ws[K * HID];
    __shared__ float as[ROWS * (K + PAD)];

    const int tid = threadIdx.x;
    const int row_base = blockIdx.x * ROWS;

    for (int i = tid; i < K * HID; i += 256) ws[i] = W[i];
    for (int i = tid; i < ROWS * K; i += 256) {
        int r = i / K, k = i - r * K;
        int gr = row_base + r;
        as[r * (K + PAD) + k] = (gr < N) ? A[(size_t)gr * K + k] : 0.0f;
    }
    __syncthreads();

    const int tx = tid & 15, ty = tid >> 4;
    const int c0 = tx * 4, r0 = ty * RT;

    float acc[RT][4];
#pragma unroll
    for (int j = 0; j < RT; j++)
#pragma unroll
        for (int i2 = 0; i2 < 4; i2++) acc[j][i2] = 0.0f;

    for (int k = 0; k < K; k += 4) {
        float4 av[RT], wv[4];
#pragma unroll
        for (int j = 0; j < RT; j++)
            av[j] = *(const float4*)&as[(r0 + j) * (K + PAD) + k];
#pragma unroll
        for (int kk = 0; kk < 4; kk++)
            wv[kk] = *(const float4*)&ws[(k + kk) * HID + c0];
#pragma unroll
        for (int j = 0; j < RT; j++) {
#pragma unroll
            for (int kk = 0; kk < 4; kk++) {
                const float a = (&av[j].x)[kk];
                acc[j][0] += a * wv[kk].x;
                acc[j][1] += a * wv[kk].y;
                acc[j][2] += a * wv[kk].z;
                acc[j][3] += a * wv[kk].w;
            }
        }
    }

#pragma unroll
    for (int j = 0; j < RT; j++) {
        const int gr = row_base + r0 + j;
        if (gr < N) {
            float4 v = make_float4(acc[j][0], acc[j][1], acc[j][2], acc[j][3]);
            if (ADD_BIAS) {
                const float4 bv = *(const float4*)&bias[c0];
                v.x += bv.x; v.y += bv.y; v.z += bv.z; v.w += bv.w;
            }
            *(float4*)&Bout[(size_t)gr * HID + c0] = v;
        }
    }
}

// ============ fused aggregate + LayerNorm (+relu+residual) ============
// one wave per node, lane = channel. acc = b + hw[row]*dinv^2 + sum_edges
// LAST=false: res = relu(LN(acc)) + res ; LAST=true: out = LN(acc)
template <bool LAST>
__global__ __launch_bounds__(256) void agg_ln_kernel(
    const int* __restrict__ off, const int* __restrict__ ssrc,
    const float* __restrict__ snorm, const float* __restrict__ dinv,
    const float* __restrict__ hw, const float* __restrict__ bias,
    const float* __restrict__ g, const float* __restrict__ beta,
    float* __restrict__ res, float* __restrict__ out, int N) {
    const int row = blockIdx.x * 4 + (threadIdx.x >> 6);
    if (row >= N) return;
    const int c = threadIdx.x & 63;
    const size_t o = (size_t)row * HID + c;

    const float di = dinv[row];
    float acc = bias[c] + hw[o] * di * di;

    int p = off[row];
    const int p1 = off[row + 1];
    if (p < p1) {
        int s = ssrc[p];
        float nm = snorm[p];
        for (++p; p < p1; ++p) {
            const int s2 = ssrc[p];
            const float nm2 = snorm[p];
            acc += hw[(size_t)s * HID + c] * nm;
            s = s2;
            nm = nm2;
        }
        acc += hw[(size_t)s * HID + c] * nm;
    }

    // LayerNorm over 64 channels (one wave)
    float su = acc;
#pragma unroll
    for (int m = 1; m < 64; m <<= 1) su += __shfl_xor(su, m);
    const float mean = su * (1.0f / 64.0f);
    const float d = acc - mean;
    float q = d * d;
#pragma unroll
    for (int m = 1; m < 64; m <<= 1) q += __shfl_xor(q, m);
    const float var = q * (1.0f / 64.0f);
    const float y = d * rsqrtf(var + 1e-5f) * g[c] + beta[c];

    if (LAST) {
        out[o] = y;
    } else {
        res[o] = fmaxf(y, 0.0f) + res[o];
    }
}

extern "C" void kernel_launch(void* const* d_in, const int* in_sizes, int n_in,
                              void* d_out, int out_size, void* d_ws, size_t ws_size,
                              hipStream_t stream) {
    const float* x      = (const float*)d_in[0];
    const int*   ei     = (const int*)d_in[1];
    const float* proj_w = (const float*)d_in[2];
    const float* proj_b = (const float*)d_in[3];
    const float* w[3]  = {(const float*)d_in[4], (const float*)d_in[8],  (const float*)d_in[12]};
    const float* b[3]  = {(const float*)d_in[5], (const float*)d_in[9],  (const float*)d_in[13]};
    const float* g[3]  = {(const float*)d_in[6], (const float*)d_in[10], (const float*)d_in[14]};
    const float* be[3] = {(const float*)d_in[7], (const float*)d_in[11], (const float*)d_in[15]};

    const int N = in_sizes[0] / IN_CH;
    const int E = in_sizes[1] / 2;
    const int* src = ei;
    const int* dst = ei + E;
    const int NB = (N + 255) / 256;

    char* wsb = (char*)d_ws;
    size_t o2 = 0;
    auto alloc = [&](size_t bytes) {
        void* p = wsb + o2;
        o2 = (o2 + bytes + 255) & ~(size_t)255;
        return p;
    };
    int*   cnt   = (int*)alloc((size_t)N * 4);
    int*   pos   = (int*)alloc((size_t)N * 4);
    int*   off   = (int*)alloc((size_t)(N + 1) * 4);
    int*   bsum  = (int*)alloc((size_t)NB * 4);
    float* dinv  = (float*)alloc((size_t)N * 4);
    int*   ssrc  = (int*)alloc((size_t)E * 4);
    float* snorm = (float*)alloc((size_t)E * 4);
    float* Abuf  = (float*)alloc((size_t)N * HID * 4);  // h / residual
    float* Bbuf  = (float*)alloc((size_t)N * HID * 4);  // hw

    // ---- CSR build ----
    hipMemsetAsync(cnt, 0, (size_t)N * 4, stream);
    hipMemsetAsync(pos, 0, (size_t)N * 4, stream);
    hist_kernel<<<(E + 255) / 256, 256, 0, stream>>>(dst, cnt, E);
    block_sum_kernel<<<NB, 256, 0, stream>>>(cnt, bsum, N);
    scan_bsum_kernel<<<1, 512, 0, stream>>>(bsum, off, NB, N, E);
    block_scan_kernel<<<NB, 256, 0, stream>>>(cnt, bsum, off, N);
    dinv_kernel<<<(N + 255) / 256, 256, 0, stream>>>(cnt, dinv, N);
    scatter_kernel<<<(E + 255) / 256, 256, 0, stream>>>(src, dst, off, pos, dinv,
                                                        ssrc, snorm, E);

    // ---- input projection: A = x @ proj_w + proj_b ----
    gemm_kernel<IN_CH, 32, true><<<(N + 31) / 32, 256, 0, stream>>>(
        x, proj_w, proj_b, Abuf, N);

    // ---- 3 GCN layers ----
    for (int l = 0; l < 3; l++) {
        gemm_kernel<HID, 64, false><<<(N + 63) / 64, 256, 0, stream>>>(
            Abuf, w[l], nullptr, Bbuf, N);
        if (l < 2) {
            agg_ln_kernel<false><<<(N + 3) / 4, 256, 0, stream>>>(
                off, ssrc, snorm, dinv, Bbuf, b[l], g[l], be[l], Abuf, nullptr, N);
        } else {
            agg_ln_kernel<true><<<(N + 3) / 4, 256, 0, stream>>>(
                off, ssrc, snorm, dinv, Bbuf, b[l], g[l], be[l], nullptr,
                (float*)d_out, N);
        }
    }
}